// Round 5
// baseline (104.166 us; speedup 1.0000x reference)
//
#include <hip/hip_runtime.h>

// RelativePositionEncoding (AF3-style), B=1, N=1024, C_Z=128.
// out[i,j,c] = W_pos[d_res][c] + W_tok[d_tok][c] + same_ent*w_ent[c] + W_chn[d_chain][c]
// W rows: [0:66) pos, [66:132) tok, 132 ent, [133:139) chain.  IN_DIM=139.
//
// R5 change vs R4: all index logic moved to prologue. Per-j packed W-row ids
// for BOTH block rows precomputed into LDS (int2). Main loop is only:
// ds_read_b64 (broadcast) -> bfe/lshl_add -> 3x ds_read_b128 -> adds -> store.
// LDS = 71168 (W, w_ent folded) + 8192 (offsets) = 79360 B -> 2 blocks/CU.

typedef float f4 __attribute__((ext_vector_type(4)));
typedef int   i2 __attribute__((ext_vector_type(2)));

constexpr int kN     = 1024;
constexpr int kRowF4 = 32;             // 128 floats = 32 x f4 per W row
constexpr int kWF4   = 139 * kRowF4;   // 4448 f4 elements

__global__ __launch_bounds__(1024) void relpos_kernel(
    const int* __restrict__ asym,
    const int* __restrict__ resi,
    const int* __restrict__ ent,
    const int* __restrict__ sym,
    const int* __restrict__ tok,
    const float* __restrict__ W,
    float* __restrict__ out)
{
    __shared__ f4 sW[kWF4];      // 71,168 B
    __shared__ i2 sOff[kN];      //  8,192 B : x = packed rows for i0, y = for i1

    const int tid = threadIdx.x;
    const f4* __restrict__ W4 = reinterpret_cast<const f4*>(W);

    // Stage W into LDS; fold w_ent (row 132) into chain rows 133..137
    // (same_ent <=> d_chain <= 4, so those rows always get +w_ent).
    for (int idx = tid; idx < kWF4; idx += 1024) {
        f4 v = W4[idx];
        if (idx >= 133 * kRowF4 && idx < 138 * kRowF4)
            v += W4[132 * kRowF4 + (idx & (kRowF4 - 1))];
        sW[idx] = v;
    }

    // Per-j packed W-row ids for both of this block's i rows.
    {
        const int j  = tid;
        const int aj = asym[j], rj = resi[j], ej = ent[j], sj = sym[j], tj = tok[j];
        i2 off;
        #pragma unroll
        for (int ii = 0; ii < 2; ++ii) {
            const int i  = blockIdx.x * 2 + ii;
            const int ai = asym[i], ri = resi[i], ei = ent[i], si = sym[i], ti = tok[i];

            int dres = min(max(ri - rj + 32, 0), 64);
            if (ai != aj) dres = 65;
            int dtok = min(max(ti - tj + 32, 0), 64);
            if (!(ai == aj && ri == rj)) dtok = 65;
            int dchn = min(max(si - sj + 2, 0), 4);
            if (ei != ej) dchn = 5;

            const int p = dres | ((66 + dtok) << 8) | ((133 + dchn) << 16);
            if (ii) off.y = p; else off.x = p;
        }
        sOff[j] = off;
    }
    __syncthreads();

    const int c4 = tid & 31;   // f4 column within the 128-wide channel dim
    const int jg = tid >> 5;   // 0..31 : j sub-index per iteration

    f4* __restrict__ out4 = reinterpret_cast<f4*>(out);
    f4* __restrict__ o0 = out4 + (size_t)(blockIdx.x * 2) * kN * kRowF4 + c4;
    f4* __restrict__ o1 = o0 + (size_t)kN * kRowF4;

    #pragma unroll 2
    for (int it = 0; it < kN / 32; ++it) {
        const int j = it * 32 + jg;
        const i2 off = sOff[j];            // broadcast ds_read_b64

        {
            const int p = off.x;
            const f4 v = sW[(p & 255) * kRowF4 + c4]
                       + sW[((p >> 8) & 255) * kRowF4 + c4]
                       + sW[((p >> 16) & 255) * kRowF4 + c4];
            o0[(size_t)j * kRowF4] = v;
        }
        {
            const int p = off.y;
            const f4 v = sW[(p & 255) * kRowF4 + c4]
                       + sW[((p >> 8) & 255) * kRowF4 + c4]
                       + sW[((p >> 16) & 255) * kRowF4 + c4];
            o1[(size_t)j * kRowF4] = v;
        }
    }
}

extern "C" void kernel_launch(void* const* d_in, const int* in_sizes, int n_in,
                              void* d_out, int out_size, void* d_ws, size_t ws_size,
                              hipStream_t stream) {
    const int*   asym = (const int*)d_in[0];
    const int*   resi = (const int*)d_in[1];
    const int*   ent  = (const int*)d_in[2];
    const int*   sym  = (const int*)d_in[3];
    const int*   tok  = (const int*)d_in[4];
    const float* W    = (const float*)d_in[5];
    float*       out  = (float*)d_out;

    relpos_kernel<<<dim3(kN / 2), dim3(1024), 0, stream>>>(asym, resi, ent, sym, tok, W, out);
}

// Round 6
// 102.579 us; speedup vs baseline: 1.0155x; 1.0155x over previous
//
#include <hip/hip_runtime.h>

// RelativePositionEncoding (AF3-style), B=1, N=1024, C_Z=128.
// out[i,j,c] = W_pos[d_res][c] + W_tok[d_tok][c] + same_ent*w_ent[c] + W_chn[d_chain][c]
// W rows: [0:66) pos, [66:132) tok, 132 ent, [133:139) chain.  IN_DIM=139.
//
// R6 change vs R4 (101.4us best): geometry only. 256 blocks x 1024 threads,
// 4 rows i per block -> 1 block/CU, 16 waves/CU (50% occupancy). Tests the
// "too many concurrent write streams / waves" hypothesis vs the fill
// kernels' 6.8 TB/s at 10.9% occupancy. Inner loop identical to R4.

typedef float f4 __attribute__((ext_vector_type(4)));

constexpr int kN     = 1024;
constexpr int kRowF4 = 32;             // 128 floats = 32 x f4 per W row
constexpr int kWF4   = 139 * kRowF4;   // 4448 f4 elements
constexpr int kRows  = 4;              // rows i per block

__global__ __launch_bounds__(1024) void relpos_kernel(
    const int* __restrict__ asym,
    const int* __restrict__ resi,
    const int* __restrict__ ent,
    const int* __restrict__ sym,
    const int* __restrict__ tok,
    const float* __restrict__ W,
    float* __restrict__ out)
{
    __shared__ f4  sW[kWF4];     // 71,168 B
    __shared__ int sKey[kN];     //  4,096 B

    const int tid = threadIdx.x;
    const f4* __restrict__ W4 = reinterpret_cast<const f4*>(W);

    // Stage W into LDS; fold w_ent (row 132) into chain rows 133..137
    // (same_ent <=> d_chain <= 4, so those rows always get +w_ent).
    for (int idx = tid; idx < kWF4; idx += 1024) {
        f4 v = W4[idx];
        if (idx >= 133 * kRowF4 && idx < 138 * kRowF4)
            v += W4[132 * kRowF4 + (idx & (kRowF4 - 1))];
        sW[idx] = v;
    }
    // Pack per-j indices: asym(2) | ent(2) | sym(2) | resi(9) | tok(10)
    {
        const int j = tid;
        sKey[j] = (asym[j] & 3) | ((ent[j] & 3) << 2) | ((sym[j] & 3) << 4)
                | ((resi[j] & 511) << 6) | ((tok[j] & 1023) << 15);
    }
    __syncthreads();

    const int c4 = tid & 31;   // f4 column within the 128-wide channel dim
    const int jg = tid >> 5;   // 0..31 : j sub-index per iteration

    f4* __restrict__ out4 = reinterpret_cast<f4*>(out);

    const int i0 = blockIdx.x * kRows;
    for (int ii = 0; ii < kRows; ++ii) {
        const int i = i0 + ii;
        // Row-i values are block-uniform -> scalar loads.
        const int ai = asym[i], ri = resi[i], ei = ent[i], si = sym[i], ti = tok[i];
        f4* __restrict__ orow = out4 + (size_t)i * kN * kRowF4 + c4;

        for (int it = 0; it < kN / 32; ++it) {
            const int j = it * 32 + jg;
            const int k = sKey[j];                 // broadcast ds_read_b32
            const int aj =  k        & 3;
            const int ej = (k >> 2)  & 3;
            const int sj = (k >> 4)  & 3;
            const int rj = (k >> 6)  & 511;
            const int tj = (k >> 15) & 1023;

            const bool same_chain = (ai == aj);
            const bool same_ent   = (ei == ej);

            int dres = min(max(ri - rj + 32, 0), 64);
            if (!same_chain) dres = 65;
            int dtok = min(max(ti - tj + 32, 0), 64);
            if (!(same_chain && (ri == rj))) dtok = 65;
            int dchn = min(max(si - sj + 2, 0), 4);
            if (!same_ent) dchn = 5;

            const f4 wa = sW[dres * kRowF4 + c4];
            const f4 wb = sW[(66 + dtok) * kRowF4 + c4];
            const f4 wc = sW[(133 + dchn) * kRowF4 + c4];

            orow[(size_t)j * kRowF4] = wa + wb + wc;
        }
    }
}

extern "C" void kernel_launch(void* const* d_in, const int* in_sizes, int n_in,
                              void* d_out, int out_size, void* d_ws, size_t ws_size,
                              hipStream_t stream) {
    const int*   asym = (const int*)d_in[0];
    const int*   resi = (const int*)d_in[1];
    const int*   ent  = (const int*)d_in[2];
    const int*   sym  = (const int*)d_in[3];
    const int*   tok  = (const int*)d_in[4];
    const float* W    = (const float*)d_in[5];
    float*       out  = (float*)d_out;

    relpos_kernel<<<dim3(kN / kRows), dim3(1024), 0, stream>>>(asym, resi, ent, sym, tok, W, out);
}